// Round 6
// baseline (644.744 us; speedup 1.0000x reference)
//
#include <hip/hip_runtime.h>
#include <hip/hip_cooperative_groups.h>
#include <cstdint>
#include <cstddef>

namespace cg = cooperative_groups;

// ---------------------------------------------------------------------------
// SOMFNN forward in TWO cooperative dispatches (one per layer).
// R5 post-mortem: 512-thr blocks with 33792B LDS -> runtime occupancy calc
// (64KB pool) gave 1 block/CU -> 256 co-resident < 512-block grid -> coop
// launch rejected silently, nothing ran (absmax ~ max|sigmoid|).
// R6: 256-thr blocks, 4-wave m97-style gemm, LDS exactly 16384B,
// launch_bounds(256,2) -> >=2 blocks/CU under any calc (needed: 2).
// Semantics (exact vs reference):
//   * stau = base/2 scalar; base = mean(||x_i||^2) - ||mean(x)||^2 from
//     cheap pre-passes => known BEFORE the gemm.
//   * prototypes never updated => distances from Gram G = X X^T; gemm
//     epilogue emits dens=exp(dist*ninv) directly, accumulating row sums S
//     (shfl-reduced, 1 atomic/row/wave) and edge flags e (atomicOr, rare).
//   * leader scan: e_i=0 => definitively NEW; stragglers resolved exactly
//     by a single-block sequential pass (T=0 for this data).
// Phases per mega (grid.sync between): P prep | Q stau | A gemm | D decide
// | L lamb.
// ---------------------------------------------------------------------------

#define DELTA_F 0.13533528323661270f  // float(exp(-2))
#define MBYTE (1u << 20)

typedef __bf16 bf16;
typedef bf16 bf16x8 __attribute__((ext_vector_type(8)));
typedef bf16 bf16x4 __attribute__((ext_vector_type(4)));
typedef float f32x4 __attribute__((ext_vector_type(4)));

typedef __attribute__((address_space(1))) void as1_void;
typedef __attribute__((address_space(3))) void as3_void;

__device__ __forceinline__ void gload16(const bf16* g, bf16* l) {
  __builtin_amdgcn_global_load_lds((as1_void*)g, (as3_void*)l, 16, 0, 0);
}

__device__ __forceinline__ float wave_reduce(float s) {
  for (int o = 32; o > 0; o >>= 1) s += __shfl_down(s, o, 64);
  return s;
}

struct MegaArgs {
  const float* xf;    // L0: x (f32)
  const bf16* hsrc;   // L1: hb
  const float* Wf;    // W0 / W1 (f32)
  const float* bias;  // b0 / b1
  bf16* Ab;           // bf16 A (xb or hb); B-cat rows >=2048 contiguous after
  bf16* Wb;           // conversion dest == Ab + 2048*2048
  float* Dens;        // 2048x2048 densities
  bf16* Hb;           // L0 sigmoid out (bf16)
  float* Fo;          // L1 sigmoid out (f32)
  float* SEN;         // 2048 row norms
  float* cpart;       // 16x2048 colsum partials
  float* scal;        // [0]=stau [1]=-1/stau
  float* S;           // 2048 density row sums
  int* e;             // 2048 edge flags
  int* as;            // assigned rule per sample
  int* rcnt;          // # reassigned
  int* rlist;         // reassigned indices
  float* lamb;        // 2048 output
};

template <bool IS_L0>
__global__ __launch_bounds__(256, 2) void mega(MegaArgs a) {
  __shared__ __align__(16) char smem[16384];
  cg::grid_group grid = cg::this_grid();
  const int tid = threadIdx.x;
  const int wave = tid >> 6, lane = tid & 63;
  const int lb = blockIdx.y * gridDim.x + blockIdx.x;

  // ============================= phase P ===================================
  if (IS_L0) {
    if (lb < 256) {  // convert x -> xb + SEN row norms (2 rows/wave)
#pragma unroll
      for (int rr = 0; rr < 2; ++rr) {
        const int row = lb * 8 + wave * 2 + rr;
        const float* src = a.xf + (size_t)row * 2048;
        bf16* dst = a.Ab + (size_t)row * 2048;
        float ss = 0.f;
        for (int c = lane * 4; c < 2048; c += 256) {
          f32x4 v = *(const f32x4*)(src + c);
          bf16x4 o;
          o.x = (bf16)v.x; o.y = (bf16)v.y; o.z = (bf16)v.z; o.w = (bf16)v.w;
          *(bf16x4*)(dst + c) = o;
          ss += v.x * v.x + v.y * v.y + v.z * v.z + v.w * v.w;
        }
        ss = wave_reduce(ss);
        if (lane == 0) a.SEN[row] = ss;
      }
    } else if (lb < 384) {  // colsum partials over x (16 row-chunks x 8 col)
      const int b = lb - 256, rc = b >> 3, cc = b & 7;
      const int col = cc * 256 + tid;
      const float* p = a.xf + (size_t)rc * 128 * 2048 + col;
      float s = 0.f;
      for (int r = 0; r < 128; ++r) s += p[(size_t)r * 2048];
      a.cpart[(size_t)rc * 2048 + col] = s;
    } else {  // convert W0 (4M elems / 128 units)
      const int b = lb - 384;
      const float* src = a.Wf + (size_t)b * 32768;
      bf16* dst = a.Wb + (size_t)b * 32768;
      for (int c = tid * 4; c < 32768; c += 1024) {
        f32x4 v = *(const f32x4*)(src + c);
        bf16x4 o;
        o.x = (bf16)v.x; o.y = (bf16)v.y; o.z = (bf16)v.z; o.w = (bf16)v.w;
        *(bf16x4*)(dst + c) = o;
      }
      if (b == 0)
        for (int i = tid; i < 2048; i += 256) { a.S[i] = 0.f; a.e[i] = 0; }
    }
  } else {
    if (lb < 128) {  // SEN row norms of hb (4 rows/wave)
#pragma unroll
      for (int rr = 0; rr < 4; ++rr) {
        const int row = lb * 16 + wave * 4 + rr;
        const bf16* src = a.hsrc + (size_t)row * 2048;
        float ss = 0.f;
        for (int c = lane * 8; c < 2048; c += 512) {
          bf16x8 v8 = *(const bf16x8*)(src + c);
#pragma unroll
          for (int q = 0; q < 8; ++q) { const float f = (float)v8[q]; ss += f * f; }
        }
        ss = wave_reduce(ss);
        if (lane == 0) a.SEN[row] = ss;
      }
    } else if (lb < 256) {  // colsum partials over hb
      const int b = lb - 128, rc = b >> 3, cc = b & 7;
      const int col = cc * 256 + tid;
      const bf16* p = a.hsrc + (size_t)rc * 128 * 2048 + col;
      float s = 0.f;
      for (int r = 0; r < 128; ++r) s += (float)p[(size_t)r * 2048];
      a.cpart[(size_t)rc * 2048 + col] = s;
    } else {  // convert W1 (2M elems / 128 units)
      const int b = lb - 256;
      const float* src = a.Wf + (size_t)b * 16384;
      bf16* dst = a.Wb + (size_t)b * 16384;
      for (int c = tid * 4; c < 16384; c += 1024) {
        f32x4 v = *(const f32x4*)(src + c);
        bf16x4 o;
        o.x = (bf16)v.x; o.y = (bf16)v.y; o.z = (bf16)v.z; o.w = (bf16)v.w;
        *(bf16x4*)(dst + c) = o;
      }
      if (b == 0)
        for (int i = tid; i < 2048; i += 256) { a.S[i] = 0.f; a.e[i] = 0; }
    }
  }
  grid.sync();

  // ============================= phase Q: stau =============================
  if (lb == 0) {
    float ssen = 0.f;
    for (int i = tid; i < 2048; i += 256) ssen += a.SEN[i];
    float sg2 = 0.f;
    for (int c = tid; c < 2048; c += 256) {
      float cs = 0.f;
#pragma unroll
      for (int p = 0; p < 16; ++p) cs += a.cpart[(size_t)p * 2048 + c];
      const float gm = cs * (1.f / 2048.f);
      sg2 += gm * gm;
    }
    float* r1 = (float*)smem;
    float* r2 = r1 + 256;
    r1[tid] = ssen; r2[tid] = sg2;
    __syncthreads();
    for (int s = 128; s; s >>= 1) {
      if (tid < s) { r1[tid] += r1[tid + s]; r2[tid] += r2[tid + s]; }
      __syncthreads();
    }
    if (tid == 0) {
      const float stau = 0.5f * (r1[0] * (1.f / 2048.f) - r2[0]);
      a.scal[0] = stau;
      a.scal[1] = -1.f / stau;
    }
  }
  grid.sync();

  // ============================= phase A: gemm =============================
  // 128x128 tile/block, 4 waves each 64x64 over full K, BK=32, swizzled LDS.
  {
    const float ninv = a.scal[1];
    const int quad = lane >> 4, l16 = lane & 15;
    const int wm = wave & 1, wn = wave >> 1;
    const int m0 = blockIdx.y * 128, n0 = blockIdx.x * 128;
    const int waveM = wm * 64, waveN = wn * 64;
    const bool isGram = (blockIdx.x < 16);
    const int sr = lane >> 2, slot = lane & 3;
    const int gk = (slot ^ (sr & 3)) * 8;  // swizzled global k offset
    const bf16* aSrc = a.Ab + (size_t)(m0 + wave * 32 + sr) * 2048 + gk;
    const bf16* bSrc = a.Ab + (size_t)(n0 + wave * 32 + sr) * 2048 + gk;
    bf16* const aDst0 = (bf16*)(smem + wave * 2048);
    bf16* const aDst1 = (bf16*)(smem + wave * 2048 + 1024);
    bf16* const bDst0 = (bf16*)(smem + 8192 + wave * 2048);
    bf16* const bDst1 = (bf16*)(smem + 8192 + wave * 2048 + 1024);
    const int rdA = (waveM + l16) * 64 + (quad ^ (l16 & 3)) * 16;
    const int rdB = 8192 + (waveN + l16) * 64 + (quad ^ (l16 & 3)) * 16;

    f32x4 acc[4][4] = {};
    for (int k0 = 0; k0 < 2048; k0 += 32) {
      gload16(aSrc + k0, aDst0);
      gload16(aSrc + 16 * 2048 + k0, aDst1);
      gload16(bSrc + k0, bDst0);
      gload16(bSrc + 16 * 2048 + k0, bDst1);
      __syncthreads();
      bf16x8 af[4], bfr[4];
#pragma unroll
      for (int i = 0; i < 4; ++i) af[i] = *(const bf16x8*)(smem + rdA + i * 1024);
#pragma unroll
      for (int j = 0; j < 4; ++j) bfr[j] = *(const bf16x8*)(smem + rdB + j * 1024);
#pragma unroll
      for (int i = 0; i < 4; ++i)
#pragma unroll
        for (int j = 0; j < 4; ++j)
          acc[i][j] = __builtin_amdgcn_mfma_f32_16x16x32_bf16(af[i], bfr[j], acc[i][j], 0, 0, 0);
      __syncthreads();
    }

    if (isGram) {
#pragma unroll
      for (int i = 0; i < 4; ++i) {
        const int rbase = m0 + waveM + i * 16 + quad * 4;
        const f32x4 si4 = *(const f32x4*)(a.SEN + rbase);
        float rp[4] = {0.f, 0.f, 0.f, 0.f};
        int er = 0;
#pragma unroll
        for (int j = 0; j < 4; ++j) {
          const int col = n0 + waveN + j * 16 + l16;
          const float sj = a.SEN[col];
#pragma unroll
          for (int r = 0; r < 4; ++r) {
            const float dens = __expf((si4[r] + sj - 2.0f * acc[i][j][r]) * ninv);
            a.Dens[(size_t)(rbase + r) * 2048 + col] = dens;
            rp[r] += dens;
            if (col < rbase + r && dens >= DELTA_F) er |= (1 << r);
          }
        }
#pragma unroll
        for (int r = 0; r < 4; ++r) {
          float v = rp[r];
          v += __shfl_xor(v, 1, 64); v += __shfl_xor(v, 2, 64);
          v += __shfl_xor(v, 4, 64); v += __shfl_xor(v, 8, 64);
          if (l16 == 0) atomicAdd(a.S + rbase + r, v);
        }
        int ef = er;
        ef |= __shfl_xor(ef, 1, 64); ef |= __shfl_xor(ef, 2, 64);
        ef |= __shfl_xor(ef, 4, 64); ef |= __shfl_xor(ef, 8, 64);
        if (l16 == 0 && ef) {
#pragma unroll
          for (int r = 0; r < 4; ++r)
            if (ef & (1 << r)) atomicOr(a.e + rbase + r, 1);
        }
      }
    } else {
#pragma unroll
      for (int i = 0; i < 4; ++i) {
        const int rbase = m0 + waveM + i * 16 + quad * 4;
#pragma unroll
        for (int j = 0; j < 4; ++j) {
          const int c2 = n0 - 2048 + waveN + j * 16 + l16;
          const float bv = a.bias[c2];
#pragma unroll
          for (int r = 0; r < 4; ++r) {
            const float hv = 1.0f / (1.0f + __expf(-(acc[i][j][r] + bv)));
            if (IS_L0) a.Hb[(size_t)(rbase + r) * 2048 + c2] = (bf16)hv;
            else a.Fo[(size_t)(rbase + r) * 1024 + c2] = hv;
          }
        }
      }
    }
  }
  grid.sync();

  // ============================= phase D: decide ===========================
  if (lb == 0) {
    char* s_flag = smem;                    // 2048
    short* s_list = (short*)(smem + 2048);  // 4096
    short* s_re = (short*)(smem + 6144);    // 4096
    int* scan = (int*)(smem + 10240);       // 1024
    float* rbest = (float*)(smem + 11264);  // 1024
    int* rbj = (int*)(smem + 12288);        // 1024
    int* s_T = (int*)(smem + 13312);
    int* s_reN = (int*)(smem + 13316);
    int cnt = 0;
#pragma unroll
    for (int k = 0; k < 8; ++k) {
      const int i = tid * 8 + k;
      const int ei = a.e[i];
      s_flag[i] = (ei == 0);
      if (ei == 0) a.as[i] = i;
      cnt += ei;
    }
    scan[tid] = cnt;
    if (tid == 0) s_reN[0] = 0;
    __syncthreads();
    for (int off = 1; off < 256; off <<= 1) {
      const int v = scan[tid];
      const int add = (tid >= off) ? scan[tid - off] : 0;
      __syncthreads();
      scan[tid] = v + add;
      __syncthreads();
    }
    int pos = scan[tid] - cnt;
#pragma unroll
    for (int k = 0; k < 8; ++k) {
      const int i = tid * 8 + k;
      if (!s_flag[i]) s_list[pos++] = (short)i;
    }
    if (tid == 255) s_T[0] = scan[255];
    __syncthreads();
    const int T = s_T[0];
    for (int t = 0; t < T; ++t) {
      const int i = s_list[t];
      const float* di = a.Dens + (size_t)i * 2048;
      float best = -1.0f;
      int bestj = 0x7fffffff;
      for (int j = tid; j < i; j += 256) {
        if (s_flag[j]) {
          const float d = di[j];
          if (d > best || (d == best && j < bestj)) { best = d; bestj = j; }
        }
      }
      rbest[tid] = best; rbj[tid] = bestj;
      __syncthreads();
      if (tid == 0) {
        float b = -1.0f;
        int bj = 0x7fffffff;
        for (int k = 0; k < 256; ++k)
          if (rbest[k] > b || (rbest[k] == b && rbj[k] < bj)) { b = rbest[k]; bj = rbj[k]; }
        if (b < DELTA_F) { s_flag[i] = 1; a.as[i] = i; }
        else { a.as[i] = bj; s_re[s_reN[0]++] = (short)i; }
      }
      __syncthreads();
    }
    const int reN = s_reN[0];
    for (int t = tid; t < reN; t += 256) a.rlist[t] = s_re[t];
    if (tid == 0) a.rcnt[0] = reN;
  }
  grid.sync();

  // ============================= phase L: lamb =============================
  if (lb < 8) {
    const int n = lb * 256 + tid;
    const int aa = a.as[n];
    float denom = a.S[n];
    const int rc = a.rcnt[0];
    for (int t = 0; t < rc; ++t) denom -= a.Dens[(size_t)n * 2048 + a.rlist[t]];
    a.lamb[n] = a.Dens[(size_t)n * 2048 + aa] / denom;
  }
}

// ------------------------------- driver ------------------------------------
extern "C" void kernel_launch(void* const* d_in, const int* in_sizes, int n_in,
                              void* d_out, int out_size, void* d_ws, size_t ws_size,
                              hipStream_t stream) {
  const float* x = (const float*)d_in[0];
  const float* W0 = (const float*)d_in[1];
  const float* b0 = (const float*)d_in[2];
  const float* W1 = (const float*)d_in[3];
  const float* b1 = (const float*)d_in[4];
  float* out = (float*)d_out;

  char* w = (char*)d_ws;
  bf16* xb = (bf16*)(w);                  // 8 MB  [L0 B-cat rows 0..2047]
  bf16* wb0 = (bf16*)(w + 8 * MBYTE);     // 8 MB  [L0 B-cat rows 2048..4095]
  bf16* hb = (bf16*)(w + 16 * MBYTE);     // 8 MB  [L1 B-cat rows 0..2047]
  bf16* wb1 = (bf16*)(w + 24 * MBYTE);    // 4 MB  [L1 B-cat rows 2048..3071]
  float* Dens = (float*)(w + 28 * MBYTE); // 16 MB densities
  float* SEN = (float*)(w + 44 * MBYTE);  // 2048
  float* S = SEN + 2048;                  // 2048
  float* scal = S + 2048;                 // 16
  int* e = (int*)(scal + 16);             // 2048
  int* as = e + 2048;                     // 2048
  int* rcnt = as + 2048;                  // 16
  int* rlist = rcnt + 16;                 // 2048
  float* cpart = (float*)(rlist + 2048);  // 16*2048

  float* lamb0 = out + (size_t)2048 * 1024;
  float* lamb1 = lamb0 + 2048;

  MegaArgs a0 = { x, nullptr, W0, b0, xb, wb0, Dens, hb, nullptr,
                  SEN, cpart, scal, S, e, as, rcnt, rlist, lamb0 };
  void* p0[] = { &a0 };
  hipLaunchCooperativeKernel((const void*)mega<true>, dim3(32, 16), dim3(256),
                             p0, 0, stream);

  MegaArgs a1 = { nullptr, hb, W1, b1, hb, wb1, Dens, nullptr, out,
                  SEN, cpart, scal, S, e, as, rcnt, rlist, lamb1 };
  void* p1[] = { &a1 };
  hipLaunchCooperativeKernel((const void*)mega<false>, dim3(24, 16), dim3(256),
                             p1, 0, stream);
}

// Round 7
// 207.507 us; speedup vs baseline: 3.1071x; 3.1071x over previous
//
#include <hip/hip_runtime.h>
#include <cstdint>
#include <cstddef>

// ---------------------------------------------------------------------------
// SOMFNN forward, 7 nodes. R6 post-mortem: cooperative mega-kernel lockstep
// killed overlap (644us). Back to R4's multi-dispatch structure (gemm K-loop
// measured 63us, 0 bank conflicts) + the one good R5/R6 idea: stau computed
// BEFORE the gemm from cheap pre-pass stats, so the Gram epilogue writes
// dens=exp(dist*ninv) directly (+S row sums +e flags) -- both 16MB edgesum
// passes eliminated -- and L0's sigmoid epilogue emits SENh/colsumH for
// layer 1 (no extra pass over h).
// Semantics (exact vs reference): stau=base/2 scalar (SENc==cn2); prototypes
// never updated => distances from Gram; e_i=0 => definitively NEW; stragglers
// resolved exactly in decide (T=0 for this data); lamb denominator = S[n]
// minus reassigned-sample densities.
// ---------------------------------------------------------------------------

#define DELTA_F 0.13533528323661270f  // float(exp(-2))
#define MBYTE (1u << 20)

typedef __bf16 bf16;
typedef bf16 bf16x8 __attribute__((ext_vector_type(8)));
typedef bf16 bf16x4 __attribute__((ext_vector_type(4)));
typedef float f32x4 __attribute__((ext_vector_type(4)));

typedef __attribute__((address_space(1))) void as1_void;
typedef __attribute__((address_space(3))) void as3_void;

__device__ __forceinline__ void gload16(const bf16* g, bf16* l) {
  __builtin_amdgcn_global_load_lds((as1_void*)g, (as3_void*)l, 16, 0, 0);
}

// ------------------------------- GEMM --------------------------------------
// C[2048, gridX*128] = A[2048,2048] * Bcat^T (Bcat = A rows ++ W rows),
// 128x128 tiles, 8 waves = 2m x 2n x 2k, BK=64, XOR-swizzled LDS (swizzle on
// global source addresses; global_load_lds dest is lane-ordered). Epilogue:
//   blockIdx.x < 16 : Gram -> dens to Dens, S row-sums, e edge flags
//   else            : sigmoid -> hb bf16 + SENh/colsumH stats (L0)
//                              | out f32 (L1)
template <bool IS_L0>
__global__ __launch_bounds__(512, 4) void gemm_fused(
    const bf16* __restrict__ A, float* __restrict__ Dens,
    bf16* __restrict__ Hb, float* __restrict__ Fo,
    const float* __restrict__ bias, const float* __restrict__ SENin,
    const float* __restrict__ ninv_p, float* __restrict__ S,
    int* __restrict__ e, float* __restrict__ SENhOut,
    float* __restrict__ colsumH) {
  __shared__ __align__(16) char smem[32768];
  const int tid = threadIdx.x;
  const int wave = tid >> 6, lane = tid & 63;
  const int quad = lane >> 4, l16 = lane & 15;
  const int kg = wave & 1, wm = (wave >> 1) & 1, wn = (wave >> 2) & 1;
  const int m0 = blockIdx.y * 128, n0 = blockIdx.x * 128;
  const int waveM = wm * 64, waveN = wn * 64;
  const bool isGram = (n0 < 2048);
  const int sr8 = lane >> 3, slot = lane & 7;
  const int gk = (slot ^ sr8) * 8;  // swizzled global k-element offset
  const bf16* aSrc = A + (size_t)(m0 + wave * 16 + sr8) * 2048 + gk;
  const bf16* bSrc = A + (size_t)(n0 + wave * 16 + sr8) * 2048 + gk;
  char* const aDst = smem + wave * 2048;
  char* const bDst = smem + 16384 + wave * 2048;
  const int swz = ((kg * 4 + quad) ^ (l16 & 7)) * 16;
  const int aOff = (waveM + l16) * 128 + swz;
  const int bOff = 16384 + (waveN + l16) * 128 + swz;

  f32x4 acc[4][4] = {};
  for (int k0 = 0; k0 < 2048; k0 += 64) {
    gload16(aSrc + k0, (bf16*)aDst);
    gload16(aSrc + 8 * 2048 + k0, (bf16*)(aDst + 1024));
    gload16(bSrc + k0, (bf16*)bDst);
    gload16(bSrc + 8 * 2048 + k0, (bf16*)(bDst + 1024));
    __syncthreads();
    bf16x8 af[4], bfr[4];
#pragma unroll
    for (int i = 0; i < 4; ++i) af[i] = *(const bf16x8*)(smem + aOff + i * 2048);
#pragma unroll
    for (int j = 0; j < 4; ++j) bfr[j] = *(const bf16x8*)(smem + bOff + j * 2048);
#pragma unroll
    for (int i = 0; i < 4; ++i)
#pragma unroll
      for (int j = 0; j < 4; ++j)
        acc[i][j] = __builtin_amdgcn_mfma_f32_16x16x32_bf16(af[i], bfr[j], acc[i][j], 0, 0, 0);
    __syncthreads();
  }

  // epilogue: merge kg=1 partials into kg=0 via LDS (2 rounds of 2 i's)
  const float ninv = ninv_p[0];
  float colp[4] = {0.f, 0.f, 0.f, 0.f};  // L0-sig col partials (over i,r)
  char* const ex = smem + (wn * 2 + wm) * 8192;
#pragma unroll
  for (int round = 0; round < 2; ++round) {
    __syncthreads();
    if (kg == 1) {
#pragma unroll
      for (int ii = 0; ii < 2; ++ii)
#pragma unroll
        for (int j = 0; j < 4; ++j)
          *(f32x4*)(ex + (ii * 4 + j) * 1024 + lane * 16) = acc[round * 2 + ii][j];
    }
    __syncthreads();
    if (kg == 0) {
#pragma unroll
      for (int ii = 0; ii < 2; ++ii) {
        const int i = round * 2 + ii;
        const int rbase = m0 + waveM + i * 16 + quad * 4;
        if (isGram) {
          const f32x4 si4 = *(const f32x4*)(SENin + rbase);
          float rp[4] = {0.f, 0.f, 0.f, 0.f};
          int er = 0;
#pragma unroll
          for (int j = 0; j < 4; ++j) {
            f32x4 v = acc[i][j] + *(const f32x4*)(ex + (ii * 4 + j) * 1024 + lane * 16);
            const int col = n0 + waveN + j * 16 + l16;
            const float sj = SENin[col];
#pragma unroll
            for (int r = 0; r < 4; ++r) {
              const float dens = __expf((si4[r] + sj - 2.0f * v[r]) * ninv);
              Dens[(size_t)(rbase + r) * 2048 + col] = dens;
              rp[r] += dens;
              if (col < rbase + r && dens >= DELTA_F) er |= (1 << r);
            }
          }
#pragma unroll
          for (int r = 0; r < 4; ++r) {
            float rv = rp[r];
            rv += __shfl_xor(rv, 1, 64); rv += __shfl_xor(rv, 2, 64);
            rv += __shfl_xor(rv, 4, 64); rv += __shfl_xor(rv, 8, 64);
            if (l16 == 0) atomicAdd(S + rbase + r, rv);
          }
          er |= __shfl_xor(er, 1, 64); er |= __shfl_xor(er, 2, 64);
          er |= __shfl_xor(er, 4, 64); er |= __shfl_xor(er, 8, 64);
          if (l16 == 0 && er) {
#pragma unroll
            for (int r = 0; r < 4; ++r)
              if ((er >> r) & 1) atomicOr(e + rbase + r, 1);
          }
        } else {
          float rn[4] = {0.f, 0.f, 0.f, 0.f};
#pragma unroll
          for (int j = 0; j < 4; ++j) {
            f32x4 v = acc[i][j] + *(const f32x4*)(ex + (ii * 4 + j) * 1024 + lane * 16);
            const int c2 = n0 - 2048 + waveN + j * 16 + l16;
            const float bv = bias[c2];
#pragma unroll
            for (int r = 0; r < 4; ++r) {
              const float hv = 1.0f / (1.0f + __expf(-(v[r] + bv)));
              if (IS_L0) {
                Hb[(size_t)(rbase + r) * 2048 + c2] = (bf16)hv;
                rn[r] += hv * hv;
                colp[j] += hv;
              } else {
                Fo[(size_t)(rbase + r) * 1024 + c2] = hv;
              }
            }
          }
          if (IS_L0) {
#pragma unroll
            for (int r = 0; r < 4; ++r) {
              float rv = rn[r];
              rv += __shfl_xor(rv, 1, 64); rv += __shfl_xor(rv, 2, 64);
              rv += __shfl_xor(rv, 4, 64); rv += __shfl_xor(rv, 8, 64);
              if (l16 == 0) atomicAdd(SENhOut + rbase + r, rv);
            }
          }
        }
      }
    }
  }
  if (IS_L0 && !isGram && kg == 0) {
#pragma unroll
    for (int j = 0; j < 4; ++j) {
      float cv = colp[j];
      cv += __shfl_xor(cv, 16, 64);
      cv += __shfl_xor(cv, 32, 64);
      if (lane < 16) atomicAdd(colsumH + (n0 - 2048 + waveN + j * 16 + lane), cv);
    }
  }
}

// --------------------------- small kernels ---------------------------------
__device__ __forceinline__ float wave_reduce(float s) {
  for (int o = 32; o > 0; o >>= 1) s += __shfl_down(s, o, 64);
  return s;
}

// grid 640: b<256 x-rows (convert+SENx+colsumX bins); b<512 W0; else W1
__global__ void f2b_all(const float* __restrict__ x, const float* __restrict__ W0,
                        const float* __restrict__ W1, bf16* __restrict__ xb,
                        bf16* __restrict__ wb0, bf16* __restrict__ wb1,
                        float* __restrict__ SENx, float* __restrict__ cpartX) {
  const int b = blockIdx.x, tid = threadIdx.x;
  const int wave = tid >> 6, lane = tid & 63;
  if (b < 256) {
    const int r0 = b * 8;
    __shared__ float ws[8][4];
    f32x4 c0 = {0.f, 0.f, 0.f, 0.f}, c1 = {0.f, 0.f, 0.f, 0.f};
    for (int r = 0; r < 8; ++r) {
      const float* src = x + (size_t)(r0 + r) * 2048;
      bf16* dst = xb + (size_t)(r0 + r) * 2048;
      f32x4 v0 = *(const f32x4*)(src + tid * 4);
      f32x4 v1 = *(const f32x4*)(src + 1024 + tid * 4);
      bf16x4 o0, o1;
      o0.x = (bf16)v0.x; o0.y = (bf16)v0.y; o0.z = (bf16)v0.z; o0.w = (bf16)v0.w;
      o1.x = (bf16)v1.x; o1.y = (bf16)v1.y; o1.z = (bf16)v1.z; o1.w = (bf16)v1.w;
      *(bf16x4*)(dst + tid * 4) = o0;
      *(bf16x4*)(dst + 1024 + tid * 4) = o1;
      c0 += v0; c1 += v1;
      float rn = v0.x * v0.x + v0.y * v0.y + v0.z * v0.z + v0.w * v0.w +
                 v1.x * v1.x + v1.y * v1.y + v1.z * v1.z + v1.w * v1.w;
      rn = wave_reduce(rn);
      if (lane == 0) ws[r][wave] = rn;
    }
    __syncthreads();
    if (tid < 8) SENx[r0 + tid] = ws[tid][0] + ws[tid][1] + ws[tid][2] + ws[tid][3];
    float* bin = cpartX + (size_t)(b & 15) * 2048;
    atomicAdd(bin + tid * 4 + 0, c0.x); atomicAdd(bin + tid * 4 + 1, c0.y);
    atomicAdd(bin + tid * 4 + 2, c0.z); atomicAdd(bin + tid * 4 + 3, c0.w);
    atomicAdd(bin + 1024 + tid * 4 + 0, c1.x); atomicAdd(bin + 1024 + tid * 4 + 1, c1.y);
    atomicAdd(bin + 1024 + tid * 4 + 2, c1.z); atomicAdd(bin + 1024 + tid * 4 + 3, c1.w);
  } else if (b < 512) {
    const size_t base = (size_t)(b - 256) * 16384;
    for (int c = tid * 4; c < 16384; c += 1024) {
      f32x4 v = *(const f32x4*)(W0 + base + c);
      bf16x4 o;
      o.x = (bf16)v.x; o.y = (bf16)v.y; o.z = (bf16)v.z; o.w = (bf16)v.w;
      *(bf16x4*)(wb0 + base + c) = o;
    }
  } else {
    const size_t base = (size_t)(b - 512) * 16384;
    for (int c = tid * 4; c < 16384; c += 1024) {
      f32x4 v = *(const f32x4*)(W1 + base + c);
      bf16x4 o;
      o.x = (bf16)v.x; o.y = (bf16)v.y; o.z = (bf16)v.z; o.w = (bf16)v.w;
      *(bf16x4*)(wb1 + base + c) = o;
    }
  }
}

// scal[0]=stau0, scal[1]=-1/stau0  (from SENx + 16-bin colsumX)
__global__ void stau0_kernel(const float* __restrict__ SENx,
                             const float* __restrict__ cpartX,
                             float* __restrict__ scal) {
  const int tid = threadIdx.x;
  float ssen = 0.f;
  for (int i = tid; i < 2048; i += 256) ssen += SENx[i];
  float sg2 = 0.f;
  for (int c = tid; c < 2048; c += 256) {
    float cs = 0.f;
#pragma unroll
    for (int p = 0; p < 16; ++p) cs += cpartX[(size_t)p * 2048 + c];
    const float gm = cs * (1.f / 2048.f);
    sg2 += gm * gm;
  }
  __shared__ float r1[256], r2[256];
  r1[tid] = ssen; r2[tid] = sg2;
  __syncthreads();
  for (int s = 128; s; s >>= 1) {
    if (tid < s) { r1[tid] += r1[tid + s]; r2[tid] += r2[tid + s]; }
    __syncthreads();
  }
  if (tid == 0) {
    const float stau = 0.5f * (r1[0] * (1.f / 2048.f) - r2[0]);
    scal[0] = stau;
    scal[1] = -1.f / stau;
  }
}

// decide (+ optional stau1 prelude) + lamb, single block.
template <bool STAU1>
__global__ void decide_lamb(const int* __restrict__ e, const float* __restrict__ Dens,
                            const float* __restrict__ S, float* __restrict__ lamb,
                            const float* __restrict__ SENh,
                            const float* __restrict__ colsumH,
                            float* __restrict__ scalOut) {
  __shared__ char s_flag[2048];
  __shared__ short s_as[2048];
  __shared__ short s_list[2048];
  __shared__ short s_re[2048];
  __shared__ int scan_[256];
  __shared__ float rbest[256];
  __shared__ int rbj[256];
  __shared__ int s_T, s_reN;
  __shared__ float r1[256], r2[256];
  const int tid = threadIdx.x;

  if (STAU1) {
    float ssen = 0.f;
    for (int i = tid; i < 2048; i += 256) ssen += SENh[i];
    float sg2 = 0.f;
    for (int c = tid; c < 2048; c += 256) {
      const float gm = colsumH[c] * (1.f / 2048.f);
      sg2 += gm * gm;
    }
    r1[tid] = ssen; r2[tid] = sg2;
    __syncthreads();
    for (int s = 128; s; s >>= 1) {
      if (tid < s) { r1[tid] += r1[tid + s]; r2[tid] += r2[tid + s]; }
      __syncthreads();
    }
    if (tid == 0) {
      const float stau = 0.5f * (r1[0] * (1.f / 2048.f) - r2[0]);
      scalOut[4] = stau;
      scalOut[5] = -1.f / stau;
    }
    __syncthreads();
  }

  int cnt = 0;
#pragma unroll
  for (int k = 0; k < 8; ++k) {
    const int i = tid * 8 + k;
    const int ei = e[i];
    s_flag[i] = (ei == 0);
    if (ei == 0) s_as[i] = (short)i;
    cnt += ei;
  }
  scan_[tid] = cnt;
  if (tid == 0) s_reN = 0;
  __syncthreads();
  for (int off = 1; off < 256; off <<= 1) {
    const int v = scan_[tid];
    const int add = (tid >= off) ? scan_[tid - off] : 0;
    __syncthreads();
    scan_[tid] = v + add;
    __syncthreads();
  }
  int pos = scan_[tid] - cnt;
#pragma unroll
  for (int k = 0; k < 8; ++k) {
    const int i = tid * 8 + k;
    if (!s_flag[i]) s_list[pos++] = (short)i;
  }
  if (tid == 255) s_T = scan_[255];
  __syncthreads();
  const int T = s_T;
  for (int t = 0; t < T; ++t) {
    const int i = s_list[t];
    const float* di = Dens + (size_t)i * 2048;
    float best = -1.0f;
    int bestj = 0x7fffffff;
    for (int j = tid; j < i; j += 256) {
      if (s_flag[j]) {
        const float d = di[j];
        if (d > best || (d == best && j < bestj)) { best = d; bestj = j; }
      }
    }
    rbest[tid] = best; rbj[tid] = bestj;
    __syncthreads();
    if (tid == 0) {
      float b = -1.0f;
      int bj = 0x7fffffff;
      for (int k = 0; k < 256; ++k)
        if (rbest[k] > b || (rbest[k] == b && rbj[k] < bj)) { b = rbest[k]; bj = rbj[k]; }
      if (b < DELTA_F) { s_flag[i] = 1; s_as[i] = (short)i; }
      else { s_as[i] = (short)bj; s_re[s_reN++] = (short)i; }
    }
    __syncthreads();
  }
  const int reN = s_reN;
  for (int n = tid; n < 2048; n += 256) {
    const int aa = s_as[n];
    const float* dn = Dens + (size_t)n * 2048;
    float denom = S[n];
    for (int t = 0; t < reN; ++t) denom -= dn[s_re[t]];
    lamb[n] = dn[aa] / denom;
  }
}

// ------------------------------- driver ------------------------------------
extern "C" void kernel_launch(void* const* d_in, const int* in_sizes, int n_in,
                              void* d_out, int out_size, void* d_ws, size_t ws_size,
                              hipStream_t stream) {
  const float* x = (const float*)d_in[0];
  const float* W0 = (const float*)d_in[1];
  const float* b0 = (const float*)d_in[2];
  const float* W1 = (const float*)d_in[3];
  const float* b1 = (const float*)d_in[4];
  float* out = (float*)d_out;

  char* w = (char*)d_ws;
  bf16* xb = (bf16*)(w);                  // 8 MB  [L0 rows 0..2047]
  bf16* wb0 = (bf16*)(w + 8 * MBYTE);     // 8 MB  [L0 rows 2048..4095]
  bf16* hb = (bf16*)(w + 16 * MBYTE);     // 8 MB  [L1 rows 0..2047]
  bf16* wb1 = (bf16*)(w + 24 * MBYTE);    // 4 MB  [L1 rows 2048..3071]
  float* Dens = (float*)(w + 28 * MBYTE); // 16 MB
  float* SENx = (float*)(w + 44 * MBYTE); // 2048 (plain stores)
  float* scal = SENx + 2048;              // 16
  // ---- zeroed region (atomic accumulators) ----
  float* zbase = scal + 16;
  float* SENh = zbase;                    // 2048
  float* cpartX = SENh + 2048;            // 16*2048
  float* colsumH = cpartX + 16 * 2048;    // 2048
  float* S0 = colsumH + 2048;             // 2048
  float* S1 = S0 + 2048;                  // 2048
  int* e0 = (int*)(S1 + 2048);            // 2048
  int* e1 = e0 + 2048;                    // 2048
  const size_t zbytes = (size_t)(2048 * 7 + 16 * 2048) * 4;

  float* lamb0 = out + (size_t)2048 * 1024;
  float* lamb1 = lamb0 + 2048;

  hipMemsetAsync(zbase, 0, zbytes, stream);
  f2b_all<<<640, 256, 0, stream>>>(x, W0, W1, xb, wb0, wb1, SENx, cpartX);
  stau0_kernel<<<1, 256, 0, stream>>>(SENx, cpartX, scal);
  gemm_fused<true><<<dim3(32, 16), 512, 0, stream>>>(
      xb, Dens, hb, nullptr, b0, SENx, scal + 1, S0, e0, SENh, colsumH);
  decide_lamb<true><<<1, 256, 0, stream>>>(e0, Dens, S0, lamb0, SENh, colsumH, scal);
  gemm_fused<false><<<dim3(24, 16), 512, 0, stream>>>(
      hb, Dens, nullptr, out, b1, SENh, scal + 5, S1, e1, nullptr, nullptr);
  decide_lamb<false><<<1, 256, 0, stream>>>(e1, Dens, S1, lamb1, nullptr, nullptr, nullptr);
}